// Round 1
// baseline (291.409 us; speedup 1.0000x reference)
//
#include <hip/hip_runtime.h>
#include <math.h>

#define NS 1024
#define NU 32
#define ND 256

static constexpr float EPS_POS = 1e-6f;
static constexpr float EPS_NEG = 1e-8f;

// ---------------------------------------------------------------------------
// Kernel 1: per-speaker centroids + positive (LOO) cosines + inverse norms.
// One block per speaker, 256 threads.
// Writes: cnT[d][t] (k-major normalized centroids), invn[s*NU+u], blk_pos[s].
// ---------------------------------------------------------------------------
__global__ __launch_bounds__(256) void ge2e_k1(
    const float* __restrict__ dv, float* __restrict__ cnT,
    float* __restrict__ invn, float* __restrict__ blk_pos)
{
    const int s = blockIdx.x;
    const int tid = threadIdx.x;
    const int wave = tid >> 6;
    const int lane = tid & 63;

    __shared__ float v[NU][ND];   // 32 KB speaker tile
    __shared__ float cs[ND];      // column sums over u
    __shared__ float red[16];

    const float* base = dv + (size_t)s * (NU * ND);
    for (int idx = tid; idx < NU * ND; idx += 256) {
        v[idx >> 8][idx & 255] = base[idx];
    }
    __syncthreads();

    // column sums (thread == dimension d)
    {
        float a = 0.f;
        #pragma unroll
        for (int u = 0; u < NU; ++u) a += v[u][tid];
        cs[tid] = a;
    }
    __syncthreads();

    // centroid norm -> normalized centroid, written transposed (k-major)
    float c = cs[tid] * (1.0f / NU);
    float p = c * c;
    #pragma unroll
    for (int off = 32; off > 0; off >>= 1) p += __shfl_xor(p, off, 64);
    if (lane == 0) red[wave] = p;
    __syncthreads();
    if (tid == 0) red[8] = red[0] + red[1] + red[2] + red[3];
    __syncthreads();
    {
        float rn = 1.0f / fmaxf(sqrtf(red[8]), EPS_NEG);
        cnT[(size_t)tid * NS + s] = c * rn;
    }

    // per-utterance stats: wave w handles u = 8w .. 8w+7
    const float inv31 = 1.0f / (NU - 1);
    float pos_part = 0.f;
    const float4 cc = *(const float4*)&cs[lane * 4];
    for (int uu = 0; uu < 8; ++uu) {
        const int u = wave * 8 + uu;
        const float4 vv = *(const float4*)&v[u][lane * 4];
        float pv = 0.f, pp = 0.f, px = 0.f;
        float pc;
        pc = (cc.x - vv.x) * inv31; pv += vv.x * vv.x; pp += pc * pc; px += vv.x * pc;
        pc = (cc.y - vv.y) * inv31; pv += vv.y * vv.y; pp += pc * pc; px += vv.y * pc;
        pc = (cc.z - vv.z) * inv31; pv += vv.z * vv.z; pp += pc * pc; px += vv.z * pc;
        pc = (cc.w - vv.w) * inv31; pv += vv.w * vv.w; pp += pc * pc; px += vv.w * pc;
        #pragma unroll
        for (int off = 32; off > 0; off >>= 1) {
            pv += __shfl_xor(pv, off, 64);
            pp += __shfl_xor(pp, off, 64);
            px += __shfl_xor(px, off, 64);
        }
        if (lane == 0) {
            float nv = sqrtf(pv), npc = sqrtf(pp);
            pos_part += px / (fmaxf(nv, EPS_POS) * fmaxf(npc, EPS_POS));
            invn[s * NU + u] = 1.0f / fmaxf(nv, EPS_NEG);
        }
    }
    if (lane == 0) red[4 + wave] = pos_part;
    __syncthreads();
    if (tid == 0) blk_pos[s] = red[4] + red[5] + red[6] + red[7];
}

// ---------------------------------------------------------------------------
// Kernel 2: fused all_cos GEMM + per-row online logsumexp (excl. own speaker)
// + global cosine sum. One block per speaker s (its 32 rows), 256 threads.
// Thread (ug=tid>>5, tg=tid&31) computes a 4u x 4t register tile, t-tile=128.
// ---------------------------------------------------------------------------
__global__ __launch_bounds__(256) void ge2e_k2(
    const float* __restrict__ dv, const float* __restrict__ cnT,
    const float* __restrict__ invn, const float* __restrict__ wp,
    const float* __restrict__ bp, float* __restrict__ blk_neg,
    float* __restrict__ blk_lse)
{
    const int s = blockIdx.x;
    const int tid = threadIdx.x;
    const int ug = tid >> 5;   // 0..7  -> u = 4*ug + i
    const int tg = tid & 31;   // 0..31 -> t = t0 + 4*tg + j

    __shared__ float rows[NU][ND];   // normalized rows (32 KB)
    __shared__ float sinv[NU];
    __shared__ float comb[16];

    const float w0 = wp[0];
    const float b0 = bp[0];

    if (tid < NU) sinv[tid] = invn[s * NU + tid];
    __syncthreads();

    const float* base = dv + (size_t)s * (NU * ND);
    for (int idx = tid; idx < NU * ND; idx += 256) {
        const int u = idx >> 8;
        rows[u][idx & 255] = base[idx] * sinv[u];
    }
    __syncthreads();

    float m[4], se[4], sm[4];
    #pragma unroll
    for (int i = 0; i < 4; ++i) { m[i] = -1e30f; se[i] = 0.f; sm[i] = 0.f; }

    for (int t0 = 0; t0 < NS; t0 += 128) {
        const int tc = t0 + 4 * tg;
        float acc[4][4];
        #pragma unroll
        for (int i = 0; i < 4; ++i)
            #pragma unroll
            for (int j = 0; j < 4; ++j) acc[i][j] = 0.f;

        for (int k0 = 0; k0 < ND; k0 += 4) {
            float4 rv[4];
            #pragma unroll
            for (int i = 0; i < 4; ++i)
                rv[i] = *(const float4*)&rows[ug * 4 + i][k0];
            float4 cv[4];
            #pragma unroll
            for (int kk = 0; kk < 4; ++kk)
                cv[kk] = *(const float4*)&cnT[(size_t)(k0 + kk) * NS + tc];
            #pragma unroll
            for (int kk = 0; kk < 4; ++kk) {
                #pragma unroll
                for (int i = 0; i < 4; ++i) {
                    const float r = (kk == 0) ? rv[i].x : (kk == 1) ? rv[i].y
                                  : (kk == 2) ? rv[i].z : rv[i].w;
                    acc[i][0] = fmaf(r, cv[kk].x, acc[i][0]);
                    acc[i][1] = fmaf(r, cv[kk].y, acc[i][1]);
                    acc[i][2] = fmaf(r, cv[kk].z, acc[i][2]);
                    acc[i][3] = fmaf(r, cv[kk].w, acc[i][3]);
                }
            }
        }

        // fold the 16 cosines into online state (skip own speaker t == s)
        #pragma unroll
        for (int i = 0; i < 4; ++i) {
            #pragma unroll
            for (int j = 0; j < 4; ++j) {
                const int t = tc + j;
                if (t != s) {
                    const float cv_ = acc[i][j];
                    sm[i] += cv_;
                    if (cv_ > m[i]) {
                        se[i] = se[i] * __expf(w0 * (m[i] - cv_)) + 1.0f;
                        m[i] = cv_;
                    } else {
                        se[i] += __expf(w0 * (cv_ - m[i]));
                    }
                }
            }
        }
    }

    // merge online states across the 32 tg-lanes of each half-wave
    #pragma unroll
    for (int mask = 1; mask <= 16; mask <<= 1) {
        #pragma unroll
        for (int i = 0; i < 4; ++i) {
            const float m2 = __shfl_xor(m[i], mask, 64);
            const float se2 = __shfl_xor(se[i], mask, 64);
            const float sm2 = __shfl_xor(sm[i], mask, 64);
            const float M = fmaxf(m[i], m2);
            se[i] = se[i] * __expf(w0 * (m[i] - M)) + se2 * __expf(w0 * (m2 - M));
            m[i] = M;
            sm[i] += sm2;
        }
    }

    if (tg == 0) {  // lanes 0 and 32 of each wave hold 4 finished rows each
        float negp = 0.f, lsep = 0.f;
        #pragma unroll
        for (int i = 0; i < 4; ++i) {
            negp += sm[i];
            lsep += w0 * m[i] + b0 + __logf(se[i]);
        }
        comb[ug * 2] = negp;
        comb[ug * 2 + 1] = lsep;
    }
    __syncthreads();
    if (tid == 0) {
        float n = 0.f, l = 0.f;
        #pragma unroll
        for (int h = 0; h < 8; ++h) { n += comb[h * 2]; l += comb[h * 2 + 1]; }
        blk_neg[s] = n;
        blk_lse[s] = l;
    }
}

// ---------------------------------------------------------------------------
// Kernel 3: final reduction of 1024 block partials -> (loss, pos_mean, neg_mean)
// ---------------------------------------------------------------------------
__global__ __launch_bounds__(256) void ge2e_k3(
    const float* __restrict__ blk_pos, const float* __restrict__ blk_neg,
    const float* __restrict__ blk_lse, const float* __restrict__ wp,
    const float* __restrict__ bp, float* __restrict__ out)
{
    const int tid = threadIdx.x;
    __shared__ float red[12];
    float p = 0.f, n = 0.f, l = 0.f;
    for (int i = tid; i < NS; i += 256) {
        p += blk_pos[i]; n += blk_neg[i]; l += blk_lse[i];
    }
    #pragma unroll
    for (int off = 32; off > 0; off >>= 1) {
        p += __shfl_xor(p, off, 64);
        n += __shfl_xor(n, off, 64);
        l += __shfl_xor(l, off, 64);
    }
    const int wave = tid >> 6, lane = tid & 63;
    if (lane == 0) { red[wave] = p; red[4 + wave] = n; red[8 + wave] = l; }
    __syncthreads();
    if (tid == 0) {
        const float ps = red[0] + red[1] + red[2] + red[3];
        const float ns = red[4] + red[5] + red[6] + red[7];
        const float ls = red[8] + red[9] + red[10] + red[11];
        const float pos_mean = ps * (1.0f / (NS * NU));
        const float neg_mean = ns / ((float)NS * (float)NU * (float)(NS - 1));
        const float lse_mean = ls * (1.0f / (NS * NU));
        const float loss = -(wp[0] * pos_mean + bp[0]) + lse_mean;
        out[0] = loss;
        out[1] = pos_mean;
        out[2] = neg_mean;
    }
}

extern "C" void kernel_launch(void* const* d_in, const int* in_sizes, int n_in,
                              void* d_out, int out_size, void* d_ws, size_t ws_size,
                              hipStream_t stream)
{
    const float* dv = (const float*)d_in[0];
    const float* w  = (const float*)d_in[1];
    const float* b  = (const float*)d_in[2];
    float* out = (float*)d_out;
    float* ws = (float*)d_ws;

    float* cnT     = ws;                  // [ND][NS] = 262144 floats (k-major)
    float* invn    = cnT + (size_t)ND * NS;   // [NS*NU] = 32768
    float* blk_pos = invn + NS * NU;      // [NS]
    float* blk_neg = blk_pos + NS;        // [NS]
    float* blk_lse = blk_neg + NS;        // [NS]

    hipLaunchKernelGGL(ge2e_k1, dim3(NS), dim3(256), 0, stream,
                       dv, cnT, invn, blk_pos);
    hipLaunchKernelGGL(ge2e_k2, dim3(NS), dim3(256), 0, stream,
                       dv, cnT, invn, w, b, blk_neg, blk_lse);
    hipLaunchKernelGGL(ge2e_k3, dim3(1), dim3(256), 0, stream,
                       blk_pos, blk_neg, blk_lse, w, b, out);
}

// Round 2
// 93.996 us; speedup vs baseline: 3.1002x; 3.1002x over previous
//
#include <hip/hip_runtime.h>
#include <math.h>

#define NS 1024
#define NU 32
#define ND 256

static constexpr float EPS_POS = 1e-6f;
static constexpr float EPS_NEG = 1e-8f;

typedef __attribute__((ext_vector_type(8))) short bf16x8;
typedef __attribute__((ext_vector_type(4))) float f32x4;

static __device__ __forceinline__ unsigned short f2bf(float f) {
    union { float f; unsigned u; } v; v.f = f;
    unsigned r = v.u + 0x7fffu + ((v.u >> 16) & 1u);   // RNE
    return (unsigned short)(r >> 16);
}

// ---------------------------------------------------------------------------
// Kernel 1: per-speaker centroids (-> bf16 normalized, row-major cnb[t][d]),
// positive (LOO) cosines, inverse row norms. One block per speaker.
// ---------------------------------------------------------------------------
__global__ __launch_bounds__(256) void ge2e_k1(
    const float* __restrict__ dv, unsigned short* __restrict__ cnb,
    float* __restrict__ invn, float* __restrict__ blk_pos)
{
    const int s = blockIdx.x;
    const int tid = threadIdx.x;
    const int wave = tid >> 6;
    const int lane = tid & 63;

    __shared__ float v[NU][ND];
    __shared__ float cs[ND];
    __shared__ float red[16];

    const float* base = dv + (size_t)s * (NU * ND);
    for (int idx = tid; idx < NU * ND; idx += 256) {
        v[idx >> 8][idx & 255] = base[idx];
    }
    __syncthreads();

    {
        float a = 0.f;
        #pragma unroll
        for (int u = 0; u < NU; ++u) a += v[u][tid];
        cs[tid] = a;
    }
    __syncthreads();

    // centroid norm -> normalized centroid in bf16, row-major [t][d]
    float c = cs[tid] * (1.0f / NU);
    float p = c * c;
    #pragma unroll
    for (int off = 32; off > 0; off >>= 1) p += __shfl_xor(p, off, 64);
    if (lane == 0) red[wave] = p;
    __syncthreads();
    if (tid == 0) red[8] = red[0] + red[1] + red[2] + red[3];
    __syncthreads();
    {
        float rn = 1.0f / fmaxf(sqrtf(red[8]), EPS_NEG);
        cnb[(size_t)s * ND + tid] = f2bf(c * rn);
    }

    // per-utterance stats: wave w handles u = 8w .. 8w+7
    const float inv31 = 1.0f / (NU - 1);
    float pos_part = 0.f;
    const float4 cc = *(const float4*)&cs[lane * 4];
    for (int uu = 0; uu < 8; ++uu) {
        const int u = wave * 8 + uu;
        const float4 vv = *(const float4*)&v[u][lane * 4];
        float pv = 0.f, pp = 0.f, px = 0.f;
        float pc;
        pc = (cc.x - vv.x) * inv31; pv += vv.x * vv.x; pp += pc * pc; px += vv.x * pc;
        pc = (cc.y - vv.y) * inv31; pv += vv.y * vv.y; pp += pc * pc; px += vv.y * pc;
        pc = (cc.z - vv.z) * inv31; pv += vv.z * vv.z; pp += pc * pc; px += vv.z * pc;
        pc = (cc.w - vv.w) * inv31; pv += vv.w * vv.w; pp += pc * pc; px += vv.w * pc;
        #pragma unroll
        for (int off = 32; off > 0; off >>= 1) {
            pv += __shfl_xor(pv, off, 64);
            pp += __shfl_xor(pp, off, 64);
            px += __shfl_xor(px, off, 64);
        }
        if (lane == 0) {
            float nv = sqrtf(pv), npc = sqrtf(pp);
            pos_part += px / (fmaxf(nv, EPS_POS) * fmaxf(npc, EPS_POS));
            invn[s * NU + u] = 1.0f / fmaxf(nv, EPS_NEG);
        }
    }
    if (lane == 0) red[4 + wave] = pos_part;
    __syncthreads();
    if (tid == 0) blk_pos[s] = red[4] + red[5] + red[6] + red[7];
}

// ---------------------------------------------------------------------------
// Kernel 2: MFMA all_cos + fused per-row online logsumexp (excl. own speaker)
// + cosine sum. One block per speaker (32 rows x 1024 cols), 4 waves.
// Wave w covers cols [256w, 256w+256) as 16 n-tiles of 16.
// mfma_f32_16x16x32_bf16: A row=lane%16,k=8*(lane/16)+v; B col=lane%16,
// k=8*(lane/16)+v; D row=(lane>>4)*4+reg, col=lane&15.
// ---------------------------------------------------------------------------
__global__ __launch_bounds__(256) void ge2e_k2(
    const float* __restrict__ dv, const unsigned short* __restrict__ cnb,
    const float* __restrict__ invn, const float* __restrict__ wp,
    const float* __restrict__ bp, float* __restrict__ blk_neg,
    float* __restrict__ blk_lse)
{
    const int s = blockIdx.x;
    const int tid = threadIdx.x;
    const int wv = tid >> 6;
    const int l  = tid & 63;
    const int lr = l & 15;    // A-row-in-tile / B-col-in-tile
    const int lg = l >> 4;    // k-group 0..3

    __shared__ unsigned short As[NU][264];   // bf16 rows, +8 shorts pad
    __shared__ float sinvs[NU];
    __shared__ float pm[4][NU], pse[4][NU], psm[4][NU];

    const float w0 = wp[0];
    const float b0 = bp[0];

    if (tid < NU) sinvs[tid] = invn[s * NU + tid];
    __syncthreads();

    // stage normalized bf16 rows into LDS (coalesced float4 reads)
    {
        const float4* dv4 = (const float4*)(dv + (size_t)s * (NU * ND));
        #pragma unroll
        for (int it = 0; it < 8; ++it) {
            const int i = tid + it * 256;       // float4 index, 2048 total
            const int u = i >> 6;               // 64 float4 per row
            const int kq = i & 63;
            float4 t4 = dv4[i];
            const float sc = sinvs[u];
            unsigned lo = (unsigned)f2bf(t4.x * sc) | ((unsigned)f2bf(t4.y * sc) << 16);
            unsigned hi = (unsigned)f2bf(t4.z * sc) | ((unsigned)f2bf(t4.w * sc) << 16);
            *(uint2*)&As[u][kq * 4] = make_uint2(lo, hi);
        }
    }
    __syncthreads();

    // load all A fragments into registers (reused across all 16 n-tiles)
    bf16x8 afr[2][8];
    #pragma unroll
    for (int mt = 0; mt < 2; ++mt)
        #pragma unroll
        for (int kt = 0; kt < 8; ++kt)
            afr[mt][kt] = *(const bf16x8*)&As[mt * 16 + lr][kt * 32 + lg * 8];

    float m8[8], se8[8], sm8[8];
    #pragma unroll
    for (int j = 0; j < 8; ++j) { m8[j] = -1e30f; se8[j] = 0.f; sm8[j] = 0.f; }

    for (int nt = 0; nt < 16; ++nt) {
        const int c0 = wv * 256 + nt * 16;
        const int t  = c0 + lr;              // this lane's output column
        const unsigned short* bbase = cnb + (size_t)t * ND + lg * 8;

        f32x4 acc0 = {0.f, 0.f, 0.f, 0.f};
        f32x4 acc1 = {0.f, 0.f, 0.f, 0.f};
        #pragma unroll
        for (int kt = 0; kt < 8; ++kt) {
            bf16x8 bf = *(const bf16x8*)(bbase + kt * 32);
            acc0 = __builtin_amdgcn_mfma_f32_16x16x32_bf16(afr[0][kt], bf, acc0, 0, 0, 0);
            acc1 = __builtin_amdgcn_mfma_f32_16x16x32_bf16(afr[1][kt], bf, acc1, 0, 0, 0);
        }

        if (t != s) {
            #pragma unroll
            for (int r = 0; r < 4; ++r) {
                {   // rows 0..15 (mtile 0): u = 4*lg + r
                    const float cv = acc0[r];
                    sm8[r] += cv;
                    if (cv > m8[r]) {
                        se8[r] = se8[r] * __expf(w0 * (m8[r] - cv)) + 1.0f;
                        m8[r] = cv;
                    } else {
                        se8[r] += __expf(w0 * (cv - m8[r]));
                    }
                }
                {   // rows 16..31 (mtile 1)
                    const float cv = acc1[r];
                    sm8[4 + r] += cv;
                    if (cv > m8[4 + r]) {
                        se8[4 + r] = se8[4 + r] * __expf(w0 * (m8[4 + r] - cv)) + 1.0f;
                        m8[4 + r] = cv;
                    } else {
                        se8[4 + r] += __expf(w0 * (cv - m8[4 + r]));
                    }
                }
            }
        }
    }

    // merge across the 16 column-lanes sharing each row (xor bits 0..3)
    #pragma unroll
    for (int mask = 1; mask <= 8; mask <<= 1) {
        #pragma unroll
        for (int j = 0; j < 8; ++j) {
            const float m2  = __shfl_xor(m8[j], mask, 64);
            const float se2 = __shfl_xor(se8[j], mask, 64);
            const float sm2 = __shfl_xor(sm8[j], mask, 64);
            const float M = fmaxf(m8[j], m2);
            se8[j] = se8[j] * __expf(w0 * (m8[j] - M)) + se2 * __expf(w0 * (m2 - M));
            m8[j] = M;
            sm8[j] += sm2;
        }
    }

    if (lr == 0) {
        #pragma unroll
        for (int r = 0; r < 4; ++r) {
            pm[wv][lg * 4 + r]      = m8[r];
            pse[wv][lg * 4 + r]     = se8[r];
            psm[wv][lg * 4 + r]     = sm8[r];
            pm[wv][16 + lg * 4 + r]  = m8[4 + r];
            pse[wv][16 + lg * 4 + r] = se8[4 + r];
            psm[wv][16 + lg * 4 + r] = sm8[4 + r];
        }
    }
    __syncthreads();

    if (tid < NU) {
        float M = pm[0][tid];
        #pragma unroll
        for (int w = 1; w < 4; ++w) M = fmaxf(M, pm[w][tid]);
        float se = 0.f, sm = 0.f;
        #pragma unroll
        for (int w = 0; w < 4; ++w) {
            se += pse[w][tid] * __expf(w0 * (pm[w][tid] - M));
            sm += psm[w][tid];
        }
        float lse = w0 * M + b0 + __logf(se);
        #pragma unroll
        for (int mask = 1; mask <= 16; mask <<= 1) {
            lse += __shfl_xor(lse, mask, 64);
            sm  += __shfl_xor(sm, mask, 64);
        }
        if (tid == 0) { blk_neg[s] = sm; blk_lse[s] = lse; }
    }
}

// ---------------------------------------------------------------------------
// Kernel 3: final reduction of 1024 block partials -> (loss, pos_mean, neg_mean)
// ---------------------------------------------------------------------------
__global__ __launch_bounds__(256) void ge2e_k3(
    const float* __restrict__ blk_pos, const float* __restrict__ blk_neg,
    const float* __restrict__ blk_lse, const float* __restrict__ wp,
    const float* __restrict__ bp, float* __restrict__ out)
{
    const int tid = threadIdx.x;
    __shared__ float red[12];
    float p = 0.f, n = 0.f, l = 0.f;
    for (int i = tid; i < NS; i += 256) {
        p += blk_pos[i]; n += blk_neg[i]; l += blk_lse[i];
    }
    #pragma unroll
    for (int off = 32; off > 0; off >>= 1) {
        p += __shfl_xor(p, off, 64);
        n += __shfl_xor(n, off, 64);
        l += __shfl_xor(l, off, 64);
    }
    const int wave = tid >> 6, lane = tid & 63;
    if (lane == 0) { red[wave] = p; red[4 + wave] = n; red[8 + wave] = l; }
    __syncthreads();
    if (tid == 0) {
        const float ps = red[0] + red[1] + red[2] + red[3];
        const float ns = red[4] + red[5] + red[6] + red[7];
        const float ls = red[8] + red[9] + red[10] + red[11];
        const float pos_mean = ps * (1.0f / (NS * NU));
        const float neg_mean = ns / ((float)NS * (float)NU * (float)(NS - 1));
        const float lse_mean = ls * (1.0f / (NS * NU));
        const float loss = -(wp[0] * pos_mean + bp[0]) + lse_mean;
        out[0] = loss;
        out[1] = pos_mean;
        out[2] = neg_mean;
    }
}

extern "C" void kernel_launch(void* const* d_in, const int* in_sizes, int n_in,
                              void* d_out, int out_size, void* d_ws, size_t ws_size,
                              hipStream_t stream)
{
    const float* dv = (const float*)d_in[0];
    const float* w  = (const float*)d_in[1];
    const float* b  = (const float*)d_in[2];
    float* out = (float*)d_out;

    unsigned short* cnb = (unsigned short*)d_ws;           // [NS][ND] bf16, 512 KB
    float* invn    = (float*)(cnb + (size_t)NS * ND);      // [NS*NU]
    float* blk_pos = invn + NS * NU;
    float* blk_neg = blk_pos + NS;
    float* blk_lse = blk_neg + NS;

    hipLaunchKernelGGL(ge2e_k1, dim3(NS), dim3(256), 0, stream,
                       dv, cnb, invn, blk_pos);
    hipLaunchKernelGGL(ge2e_k2, dim3(NS), dim3(256), 0, stream,
                       dv, cnb, invn, w, b, blk_neg, blk_lse);
    hipLaunchKernelGGL(ge2e_k3, dim3(1), dim3(256), 0, stream,
                       blk_pos, blk_neg, blk_lse, w, b, out);
}

// Round 3
// 50.249 us; speedup vs baseline: 5.7993x; 1.8706x over previous
//
#include <hip/hip_runtime.h>
#include <math.h>

#define NS 1024
#define NU 32
#define ND 256
#define BROWS 128
#define NBLK ((NS * NU) / BROWS)   // 256 blocks for k2

static constexpr float EPS_POS = 1e-6f;
static constexpr float EPS_NEG = 1e-8f;

typedef __attribute__((ext_vector_type(8))) short bf16x8;
typedef __attribute__((ext_vector_type(4))) float f32x4;

#if __has_builtin(__builtin_amdgcn_exp2f)
#define EXP2F(x) __builtin_amdgcn_exp2f(x)
#else
#define EXP2F(x) exp2f(x)
#endif

static __device__ __forceinline__ unsigned short f2bf(float f) {
    union { float f; unsigned u; } v; v.f = f;
    unsigned r = v.u + 0x7fffu + ((v.u >> 16) & 1u);   // RNE
    return (unsigned short)(r >> 16);
}

// ---------------------------------------------------------------------------
// Kernel 1: per-speaker centroids (-> bf16 normalized, row-major cnb[t][d]),
// positive (LOO) cosines, inverse row norms. One block per speaker.
// ---------------------------------------------------------------------------
__global__ __launch_bounds__(256) void ge2e_k1(
    const float* __restrict__ dv, unsigned short* __restrict__ cnb,
    float* __restrict__ invn, float* __restrict__ blk_pos)
{
    const int s = blockIdx.x;
    const int tid = threadIdx.x;
    const int wave = tid >> 6;
    const int lane = tid & 63;

    __shared__ float v[NU][ND];
    __shared__ float cs[ND];
    __shared__ float red[16];

    const float* base = dv + (size_t)s * (NU * ND);
    for (int idx = tid; idx < NU * ND; idx += 256) {
        v[idx >> 8][idx & 255] = base[idx];
    }
    __syncthreads();

    {
        float a = 0.f;
        #pragma unroll
        for (int u = 0; u < NU; ++u) a += v[u][tid];
        cs[tid] = a;
    }
    __syncthreads();

    // centroid norm -> normalized centroid in bf16, row-major [t][d]
    float c = cs[tid] * (1.0f / NU);
    float p = c * c;
    #pragma unroll
    for (int off = 32; off > 0; off >>= 1) p += __shfl_xor(p, off, 64);
    if (lane == 0) red[wave] = p;
    __syncthreads();
    if (tid == 0) red[8] = red[0] + red[1] + red[2] + red[3];
    __syncthreads();
    {
        float rn = 1.0f / fmaxf(sqrtf(red[8]), EPS_NEG);
        cnb[(size_t)s * ND + tid] = f2bf(c * rn);
    }

    // per-utterance stats: wave w handles u = 8w .. 8w+7
    const float inv31 = 1.0f / (NU - 1);
    float pos_part = 0.f;
    const float4 cc = *(const float4*)&cs[lane * 4];
    for (int uu = 0; uu < 8; ++uu) {
        const int u = wave * 8 + uu;
        const float4 vv = *(const float4*)&v[u][lane * 4];
        float pv = 0.f, pp = 0.f, px = 0.f;
        float pc;
        pc = (cc.x - vv.x) * inv31; pv += vv.x * vv.x; pp += pc * pc; px += vv.x * pc;
        pc = (cc.y - vv.y) * inv31; pv += vv.y * vv.y; pp += pc * pc; px += vv.y * pc;
        pc = (cc.z - vv.z) * inv31; pv += vv.z * vv.z; pp += pc * pc; px += vv.z * pc;
        pc = (cc.w - vv.w) * inv31; pv += vv.w * vv.w; pp += pc * pc; px += vv.w * pc;
        #pragma unroll
        for (int off = 32; off > 0; off >>= 1) {
            pv += __shfl_xor(pv, off, 64);
            pp += __shfl_xor(pp, off, 64);
            px += __shfl_xor(px, off, 64);
        }
        if (lane == 0) {
            float nv = sqrtf(pv), npc = sqrtf(pp);
            pos_part += px / (fmaxf(nv, EPS_POS) * fmaxf(npc, EPS_POS));
            invn[s * NU + u] = 1.0f / fmaxf(nv, EPS_NEG);
        }
    }
    if (lane == 0) red[4 + wave] = pos_part;
    __syncthreads();
    if (tid == 0) blk_pos[s] = red[4] + red[5] + red[6] + red[7];
}

// ---------------------------------------------------------------------------
// Kernel 2: m-blocked MFMA GEMM (128 rows x 1024 cols, K=256) with fused
// fixed-reference sum-exp epilogue. 256 blocks x 512 threads (8 waves =
// 2 m-groups x 4 n-groups). A (4 m-tiles) lives in registers per wave;
// B double-buffered in LDS via global_load_lds with involutive granule
// swizzle (gc ^= row&7) applied on BOTH source and read (rule 21).
// ---------------------------------------------------------------------------
__global__ __launch_bounds__(512, 2) void ge2e_k2(
    const float* __restrict__ dv, const unsigned short* __restrict__ cnb,
    const float* __restrict__ invn, const float* __restrict__ wp,
    const float* __restrict__ bp, float* __restrict__ blk_neg,
    float* __restrict__ blk_lse)
{
    const int b  = blockIdx.x;
    const int r0 = b * BROWS;
    const int tid = threadIdx.x;
    const int w  = tid >> 6;
    const int l  = tid & 63;
    const int lr = l & 15;
    const int lg = l >> 4;
    const int mg = w >> 2;   // 0..1: rows mg*64 .. +64
    const int ng = w & 3;    // 0..3: cols ng*256 .. +256

    __shared__ unsigned short Al[BROWS][264];          // 67.6 KB (pad +8)
    __shared__ unsigned short Bst[2][4][16][256];      // 64 KB double buffer
    __shared__ float sinv[BROWS];
    __shared__ float pse[4][BROWS];
    __shared__ float psm[4][BROWS];
    __shared__ float redn[2], redl[2];

    const float w0 = wp[0];
    const float b0 = bp[0];
    const float c2 = w0 * 1.4426950408889634f;   // w0 * log2(e)

    if (tid < BROWS) sinv[tid] = invn[r0 + tid];

    // per-lane permuted stage sources: LDS granule gi holds cnb granule
    // (row rrs of the 16-col tile, k-granule gcs ^ (rrs&7))
    size_t srcb[4];
    unsigned ldso[4];
    #pragma unroll
    for (int i = 0; i < 4; ++i) {
        const int gi = w * 256 + i * 64 + l;
        const int ngs = gi >> 9, g = gi & 511, rrs = g >> 5, gcs = g & 31;
        srcb[i] = (size_t)((ngs * 256 + rrs) * 32 + (gcs ^ (rrs & 7))) * 16;
        ldso[i] = (unsigned)(w * 256 + i * 64) * 16;   // wave-uniform
    }
    const char* cnbc = (const char*)cnb;

    // issue B stage 0
    #pragma unroll
    for (int i = 0; i < 4; ++i) {
        __builtin_amdgcn_global_load_lds(
            (const __attribute__((address_space(1))) void*)(cnbc + srcb[i]),
            (__attribute__((address_space(3))) void*)((char*)&Bst[0][0][0][0] + ldso[i]),
            16, 0, 0);
    }
    __syncthreads();   // sinv visible (drains B0 too)

    // cooperative A staging: dv -> normalized bf16 rows in Al (coalesced)
    #pragma unroll
    for (int r = 0; r < 8; ++r) {
        const int i = tid + r * 512;
        const int row = i >> 5, g = i & 31;
        const float* src = dv + (size_t)(r0 + row) * ND + g * 8;
        const float4 x = *(const float4*)src;
        const float4 y = *(const float4*)(src + 4);
        const float sc = sinv[row];
        uint4 pk;
        pk.x = (unsigned)f2bf(x.x * sc) | ((unsigned)f2bf(x.y * sc) << 16);
        pk.y = (unsigned)f2bf(x.z * sc) | ((unsigned)f2bf(x.w * sc) << 16);
        pk.z = (unsigned)f2bf(y.x * sc) | ((unsigned)f2bf(y.y * sc) << 16);
        pk.w = (unsigned)f2bf(y.z * sc) | ((unsigned)f2bf(y.w * sc) << 16);
        *(uint4*)&Al[row][g * 8] = pk;
    }
    __syncthreads();

    // A fragments to registers (128 VGPR), reused for all 16 steps
    bf16x8 afr[4][8];
    #pragma unroll
    for (int mt = 0; mt < 4; ++mt)
        #pragma unroll
        for (int kt = 0; kt < 8; ++kt)
            afr[mt][kt] = *(const bf16x8*)&Al[mg * 64 + mt * 16 + lr][kt * 32 + lg * 8];

    float se[4][4], sm[4][4];
    #pragma unroll
    for (int mt = 0; mt < 4; ++mt)
        #pragma unroll
        for (int r = 0; r < 4; ++r) { se[mt][r] = 0.f; sm[mt][r] = 0.f; }

    const int rsw = lr & 7;
    int town[4];
    #pragma unroll
    for (int mt = 0; mt < 4; ++mt) town[mt] = (r0 + mg * 64 + mt * 16) >> 5;

    #pragma unroll 2
    for (int j = 0; j < 16; ++j) {
        // issue next B stage first (stays in flight under the MFMAs)
        if (j < 15) {
            char* bdst = (char*)&Bst[(j + 1) & 1][0][0][0];
            const size_t soff = (size_t)(j + 1) * 8192;
            #pragma unroll
            for (int i = 0; i < 4; ++i) {
                __builtin_amdgcn_global_load_lds(
                    (const __attribute__((address_space(1))) void*)(cnbc + srcb[i] + soff),
                    (__attribute__((address_space(3))) void*)(bdst + ldso[i]),
                    16, 0, 0);
            }
        }

        const unsigned short (*bc)[16][256] = Bst[j & 1];
        f32x4 acc[4];
        #pragma unroll
        for (int mt = 0; mt < 4; ++mt) acc[mt] = (f32x4){0.f, 0.f, 0.f, 0.f};

        #pragma unroll
        for (int kt = 0; kt < 8; ++kt) {
            const bf16x8 bfr = *(const bf16x8*)&bc[ng][lr][(((kt * 4 + lg) ^ rsw)) * 8];
            #pragma unroll
            for (int mt = 0; mt < 4; ++mt)
                acc[mt] = __builtin_amdgcn_mfma_f32_16x16x32_bf16(afr[mt][kt], bfr, acc[mt], 0, 0, 0);
        }

        // branchless fixed-reference fold: cos <= 1 => M = 1
        #pragma unroll
        for (int mt = 0; mt < 4; ++mt)
            #pragma unroll
            for (int r = 0; r < 4; ++r) {
                const float cv = acc[mt][r];
                se[mt][r] += EXP2F(fmaf(c2, cv, -c2));
                sm[mt][r] += cv;
            }

        // own-speaker column: wave-uniform step test, 4-lane subtract
        #pragma unroll
        for (int mt = 0; mt < 4; ++mt) {
            if (ng == (town[mt] >> 8) && j == ((town[mt] >> 4) & 15)) {
                if (lr == (town[mt] & 15)) {
                    #pragma unroll
                    for (int r = 0; r < 4; ++r) {
                        const float cv = acc[mt][r];
                        se[mt][r] -= EXP2F(fmaf(c2, cv, -c2));
                        sm[mt][r] -= cv;
                    }
                }
            }
        }

        __syncthreads();   // next stage landed; all waves done with bc
    }

    // reduce across the 16 column-lanes (xor bits 0..3)
    #pragma unroll
    for (int mask = 1; mask <= 8; mask <<= 1)
        #pragma unroll
        for (int mt = 0; mt < 4; ++mt)
            #pragma unroll
            for (int r = 0; r < 4; ++r) {
                se[mt][r] += __shfl_xor(se[mt][r], mask, 64);
                sm[mt][r] += __shfl_xor(sm[mt][r], mask, 64);
            }

    if (lr == 0) {
        #pragma unroll
        for (int mt = 0; mt < 4; ++mt)
            #pragma unroll
            for (int r = 0; r < 4; ++r) {
                const int row = mg * 64 + mt * 16 + lg * 4 + r;
                pse[ng][row] = se[mt][r];
                psm[ng][row] = sm[mt][r];
            }
    }
    __syncthreads();

    if (tid < BROWS) {
        float st = 0.f, smt = 0.f;
        #pragma unroll
        for (int q = 0; q < 4; ++q) { st += pse[q][tid]; smt += psm[q][tid]; }
        float lse = w0 + b0 + __logf(st);
        #pragma unroll
        for (int mask = 1; mask <= 32; mask <<= 1) {
            lse += __shfl_xor(lse, mask, 64);
            smt += __shfl_xor(smt, mask, 64);
        }
        if ((tid & 63) == 0) { redn[tid >> 6] = smt; redl[tid >> 6] = lse; }
    }
    __syncthreads();
    if (tid == 0) {
        blk_neg[b] = redn[0] + redn[1];
        blk_lse[b] = redl[0] + redl[1];
    }
}

// ---------------------------------------------------------------------------
// Kernel 3: final reduction -> (loss, pos_mean, neg_mean)
// ---------------------------------------------------------------------------
__global__ __launch_bounds__(256) void ge2e_k3(
    const float* __restrict__ blk_pos, const float* __restrict__ blk_neg,
    const float* __restrict__ blk_lse, const float* __restrict__ wp,
    const float* __restrict__ bp, float* __restrict__ out)
{
    const int tid = threadIdx.x;
    __shared__ float red[12];
    float p = 0.f, n = 0.f, l = 0.f;
    for (int i = tid; i < NS; i += 256) p += blk_pos[i];
    if (tid < NBLK) { n = blk_neg[tid]; l = blk_lse[tid]; }
    #pragma unroll
    for (int off = 32; off > 0; off >>= 1) {
        p += __shfl_xor(p, off, 64);
        n += __shfl_xor(n, off, 64);
        l += __shfl_xor(l, off, 64);
    }
    const int wave = tid >> 6, lane = tid & 63;
    if (lane == 0) { red[wave] = p; red[4 + wave] = n; red[8 + wave] = l; }
    __syncthreads();
    if (tid == 0) {
        const float ps = red[0] + red[1] + red[2] + red[3];
        const float ns = red[4] + red[5] + red[6] + red[7];
        const float ls = red[8] + red[9] + red[10] + red[11];
        const float pos_mean = ps * (1.0f / (NS * NU));
        const float neg_mean = ns / ((float)NS * (float)NU * (float)(NS - 1));
        const float lse_mean = ls * (1.0f / (NS * NU));
        const float loss = -(wp[0] * pos_mean + bp[0]) + lse_mean;
        out[0] = loss;
        out[1] = pos_mean;
        out[2] = neg_mean;
    }
}

extern "C" void kernel_launch(void* const* d_in, const int* in_sizes, int n_in,
                              void* d_out, int out_size, void* d_ws, size_t ws_size,
                              hipStream_t stream)
{
    const float* dv = (const float*)d_in[0];
    const float* w  = (const float*)d_in[1];
    const float* b  = (const float*)d_in[2];
    float* out = (float*)d_out;

    unsigned short* cnb = (unsigned short*)d_ws;           // [NS][ND] bf16, 512 KB
    float* invn    = (float*)(cnb + (size_t)NS * ND);      // [NS*NU]
    float* blk_pos = invn + NS * NU;                       // [NS]
    float* blk_neg = blk_pos + NS;                         // [NBLK]
    float* blk_lse = blk_neg + NBLK;                       // [NBLK]

    hipLaunchKernelGGL(ge2e_k1, dim3(NS), dim3(256), 0, stream,
                       dv, cnb, invn, blk_pos);
    hipLaunchKernelGGL(ge2e_k2, dim3(NBLK), dim3(512), 0, stream,
                       dv, cnb, invn, w, b, blk_neg, blk_lse);
    hipLaunchKernelGGL(ge2e_k3, dim3(1), dim3(256), 0, stream,
                       blk_pos, blk_neg, blk_lse, w, b, out);
}